// Round 10
// baseline (115.679 us; speedup 1.0000x reference)
//
#include <hip/hip_runtime.h>
#include <stdint.h>

// ---------------------------------------------------------------------------
// AVNNType1Linear: out[b,o,0] = relu(sum_k x[b,k,0]*W[o,k] + bias[o])
//                  out[b,o,1] = (sum_k x[b,k,0] + sum_k x[b,k,1]) / (2*K)
// M=2048, N=4096, K=4096 fp32.
// r10: r9 phase schedule with the two races fixed:
//   (1) 3-slot LDS rotation (144 KiB) so STAGE(t+2) never hits a live slot;
//   (2) tile-end order vmcnt -> sched_barrier -> s_barrier (wait own DMA,
//       THEN join waves) as in r3/r4.
// Per K-tile: 2 phases {8 ds_read + 3 stage-loads, bar, lgkm0, setprio,
// 16 MFMA, setprio, bar}; counted vmcnt(6) once per tile (never 0 till tail).
// ---------------------------------------------------------------------------

typedef __bf16 bf16x8_t __attribute__((ext_vector_type(8)));
typedef float f32x4_t __attribute__((ext_vector_type(4)));
typedef __attribute__((address_space(1))) void gvoid_t;
typedef __attribute__((address_space(3))) void lvoid_t;

__device__ __forceinline__ uint32_t f32_to_bf16_rne(float f) {
    uint32_t u = __float_as_uint(f);
    return (u + 0x7fffu + ((u >> 16) & 1u)) >> 16;
}

// 3-bit XOR swizzle (verified conflict-free in r3/r4): spread 16B-slot
// bits[6:4] by row&7 (row = byte>>7 for 128B rows).
__device__ __forceinline__ uint32_t swz(uint32_t b) {
    return b ^ (((b >> 7) & 7u) << 4);
}

__device__ __forceinline__ bf16x8_t ds_read128(uint32_t addr) {
    bf16x8_t d;
    asm volatile("ds_read_b128 %0, %1" : "=&v"(d) : "v"(addr));
    return d;
}

// ---- kernel 1: convert activation channel to bf16 row-major + row stats ----
__global__ __launch_bounds__(256) void convert_x_stats(
    const float4* __restrict__ x4,   // [B][DIN/2] float4 = (a0,c0,a1,c1)
    uint32_t* __restrict__ abf,      // [B][DIN/2] packed 2xbf16 (may be null)
    float* __restrict__ val, int din) {
    const int row = blockIdx.x;
    const int t = threadIdx.x;
    const int f4pr = din >> 1;
    const float4* xr = x4 + (size_t)row * f4pr;
    float s = 0.f;
    if (abf != nullptr) {
        uint32_t* ar = abf + ((size_t)row * din >> 1);
        for (int i = t; i < f4pr; i += 256) {
            float4 v = xr[i];
            s += (v.x + v.y) + (v.z + v.w);
            ar[i] = f32_to_bf16_rne(v.x) | (f32_to_bf16_rne(v.z) << 16);
        }
    } else {
        for (int i = t; i < f4pr; i += 256) {
            float4 v = xr[i];
            s += (v.x + v.y) + (v.z + v.w);
        }
    }
#pragma unroll
    for (int off = 32; off; off >>= 1) s += __shfl_down(s, off, 64);
    __shared__ float red[4];
    if ((t & 63) == 0) red[t >> 6] = s;
    __syncthreads();
    if (t == 0) val[row] = (red[0] + red[1] + red[2] + red[3]) / (float)(2 * din);
}

// ---- kernel 2: W -> row-major bf16 (r4, verified) ----
__global__ __launch_bounds__(256) void convert_w(
    const float4* __restrict__ w4, uint2* __restrict__ wbf, int n4) {
    const int i = blockIdx.x * 256 + threadIdx.x;
    if (i < n4) {
        float4 v = w4[i];
        uint2 p;
        p.x = f32_to_bf16_rne(v.x) | (f32_to_bf16_rne(v.y) << 16);
        p.y = f32_to_bf16_rne(v.z) | (f32_to_bf16_rne(v.w) << 16);
        wbf[i] = p;
    }
}

// ---- kernel 3: 128x256 phase-scheduled bf16 MFMA GEMM, 3-slot LDS ----
#define BKB 128              // BK bytes per row (64 bf16)
#define A_SLAB 16384         // 128 x 64 x 2B
#define B_SLAB 32768         // 256 x 64 x 2B
#define B_BASE (3 * A_SLAB)
#define LDS_BYTES (B_BASE + 3 * B_SLAB)   // 144 KiB, 1 block/CU

__global__ __launch_bounds__(512, 1) void gemm_ph(
    const uint16_t* __restrict__ Abf, const uint16_t* __restrict__ Wbf,
    const float* __restrict__ bias, const float* __restrict__ val,
    float* __restrict__ out, int M, int N, int K) {
    extern __shared__ char lds[];
    const uint32_t lds0 = (uint32_t)(uintptr_t)(lvoid_t*)lds;

    const int tid = threadIdx.x;
    const int wv = tid >> 6;
    const int lane = tid & 63;
    const int lrow = lane & 15, lkg = lane >> 4;
    const int m0 = blockIdx.y * 128;
    const int n0 = blockIdx.x * 256;
    const int wr = wv >> 2, wc = wv & 3;    // 2m x 4n

    // staging: linear LDS dest chunk c holds swizzled tile byte swz(c*16)
    // -> pre-swizzled per-lane global source (rule #21; r3/r4-verified)
    uint32_t asrc[2], bsrc[4];
#pragma unroll
    for (int l = 0; l < 2; ++l) {
        uint32_t sb = swz((uint32_t)(l * 512 + tid) * 16u);
        asrc[l] = (uint32_t)(m0 + (int)(sb >> 7)) * (uint32_t)(K * 2) + (sb & 127u);
    }
#pragma unroll
    for (int l = 0; l < 4; ++l) {
        uint32_t sb = swz((uint32_t)(l * 512 + tid) * 16u);
        bsrc[l] = (uint32_t)(n0 + (int)(sb >> 7)) * (uint32_t)(K * 2) + (sb & 127u);
    }
    // swizzled LDS read offsets, ks0; ks1 = ^64 (bit6 lives in the swz field)
    uint32_t ard[4], brd[4];
#pragma unroll
    for (int m = 0; m < 4; ++m)
        ard[m] = swz((uint32_t)(wr * 64 + m * 16 + lrow) * 128u + (uint32_t)(lkg * 16));
#pragma unroll
    for (int n = 0; n < 4; ++n)
        brd[n] = swz((uint32_t)(wc * 64 + n * 16 + lrow) * 128u + (uint32_t)(lkg * 16));

    f32x4_t acc[4][4];
#pragma unroll
    for (int i = 0; i < 4; ++i)
#pragma unroll
        for (int j = 0; j < 4; ++j) acc[i][j] = (f32x4_t){0.f, 0.f, 0.f, 0.f};

    const int NT = K >> 6;

    // staging slices (6 loads/thread per K-tile, split 3 + 3 across phases)
#define STAGE_P0(tt)                                                          \
    {                                                                         \
        const int slot = (tt) % 3;                                            \
        _Pragma("unroll") for (int l = 0; l < 2; ++l) {                       \
            const char* src = (const char*)Abf + asrc[l] + (size_t)(tt) * BKB;\
            char* dst = lds + slot * A_SLAB + (l * 512 + wv * 64) * 16;       \
            __builtin_amdgcn_global_load_lds((gvoid_t*)src, (lvoid_t*)dst,    \
                                             16, 0, 0);                       \
        }                                                                     \
        {                                                                     \
            const char* src = (const char*)Wbf + bsrc[0] + (size_t)(tt) * BKB;\
            char* dst = lds + B_BASE + slot * B_SLAB + (wv * 64) * 16;        \
            __builtin_amdgcn_global_load_lds((gvoid_t*)src, (lvoid_t*)dst,    \
                                             16, 0, 0);                       \
        }                                                                     \
    }
#define STAGE_P1(tt)                                                          \
    {                                                                         \
        const int slot = (tt) % 3;                                            \
        _Pragma("unroll") for (int l = 1; l < 4; ++l) {                       \
            const char* src = (const char*)Wbf + bsrc[l] + (size_t)(tt) * BKB;\
            char* dst = lds + B_BASE + slot * B_SLAB + (l * 512 + wv * 64) * 16;\
            __builtin_amdgcn_global_load_lds((gvoid_t*)src, (lvoid_t*)dst,    \
                                             16, 0, 0);                       \
        }                                                                     \
    }
    // one phase: 8 ds_reads (ks), optional stage slice, bar, lgkm0, 16 MFMA
    // TAIL_CODE runs after MFMA, before the phase-closing barrier.
#define PHASE(la, lb, ksx, STAGE_CODE, TAIL_CODE)                             \
    {                                                                         \
        bf16x8_t af[4], bfr[4];                                               \
        _Pragma("unroll") for (int m = 0; m < 4; ++m)                         \
            af[m] = ds_read128((la) + (ard[m] ^ (ksx)));                      \
        _Pragma("unroll") for (int n = 0; n < 4; ++n)                         \
            bfr[n] = ds_read128((lb) + (brd[n] ^ (ksx)));                     \
        STAGE_CODE;                                                           \
        __builtin_amdgcn_s_barrier();                                         \
        asm volatile("s_waitcnt lgkmcnt(0)" ::: "memory");                    \
        __builtin_amdgcn_sched_barrier(0);                                    \
        __builtin_amdgcn_s_setprio(1);                                        \
        _Pragma("unroll") for (int m = 0; m < 4; ++m)                         \
            _Pragma("unroll") for (int n = 0; n < 4; ++n)                     \
                acc[m][n] = __builtin_amdgcn_mfma_f32_16x16x32_bf16(          \
                    af[m], bfr[n], acc[m][n], 0, 0, 0);                       \
        __builtin_amdgcn_s_setprio(0);                                        \
        TAIL_CODE;                                                            \
        __builtin_amdgcn_s_barrier();                                         \
    }
#define WAIT6  { asm volatile("s_waitcnt vmcnt(6)" ::: "memory");             \
                 __builtin_amdgcn_sched_barrier(0); }
#define WAIT0  { asm volatile("s_waitcnt vmcnt(0)" ::: "memory");             \
                 __builtin_amdgcn_sched_barrier(0); }

    // prologue: tiles 0 and 1 in flight; vmcnt(6) completes tile 0, then join
    STAGE_P0(0); STAGE_P1(0);
    if (NT > 1) { STAGE_P0(1); STAGE_P1(1); }
    if (NT > 1) { WAIT6; } else { WAIT0; }
    __builtin_amdgcn_s_barrier();

    for (int t = 0; t < NT; ++t) {
        const int slot = t % 3;
        const uint32_t la = lds0 + slot * A_SLAB;
        const uint32_t lb = lds0 + B_BASE + slot * B_SLAB;
        if (t + 2 < NT) {
            // steady state: stage t+2, end-of-tile counted wait (6 in flight)
            PHASE(la, lb, 0u, STAGE_P0(t + 2), );
            PHASE(la, lb, 64u, STAGE_P1(t + 2), WAIT6);
        } else if (t + 1 < NT) {
            // t = NT-2: nothing to stage; drain tile NT-1 fully before join
            PHASE(la, lb, 0u, , );
            PHASE(la, lb, 64u, , WAIT0);
        } else {
            // t = NT-1: last tile, no wait needed
            PHASE(la, lb, 0u, , );
            PHASE(la, lb, 64u, , );
        }
    }
#undef PHASE
#undef STAGE_P0
#undef STAGE_P1
#undef WAIT6
#undef WAIT0

    // ---------------- epilogue: bias + relu + val interleave ----------------
    const int gmb = m0 + wr * 64;
    const int gnb = n0 + wc * 64;
    float bcol[4];
#pragma unroll
    for (int n = 0; n < 4; ++n) bcol[n] = bias[gnb + n * 16 + lrow];
#pragma unroll
    for (int m = 0; m < 4; ++m) {
#pragma unroll
        for (int r = 0; r < 4; ++r) {
            const int row = gmb + m * 16 + lkg * 4 + r;
            const float vr = val[row];
            float2* orow = (float2*)(out + (size_t)row * N * 2);
#pragma unroll
            for (int n = 0; n < 4; ++n) {
                const int col = gnb + n * 16 + lrow;
                float a = fmaxf(acc[m][n][r] + bcol[n], 0.f);
                orow[col] = make_float2(a, vr);
            }
        }
    }
}

// ---- fallback (small ws): reg-staged fp32->bf16 128x128 GEMM ----
__global__ __launch_bounds__(256) void gemm_fallback(
    const float* __restrict__ xf, const float* __restrict__ Wf,
    const float* __restrict__ bias, const float* __restrict__ val,
    float* __restrict__ out, int M, int N, int K) {
    __shared__ uint16_t lA[128 * 32];
    __shared__ uint16_t lB[128 * 32];
    const int tid = threadIdx.x;
    const int wv = tid >> 6;
    const int lane = tid & 63;
    const int lrow = lane & 15;
    const int lkg = lane >> 4;
    const int m0 = blockIdx.y * 128;
    const int n0 = blockIdx.x * 128;
    const int wr = wv >> 1, wc = wv & 1;
    f32x4_t acc[4][4];
#pragma unroll
    for (int i = 0; i < 4; ++i)
#pragma unroll
        for (int j = 0; j < 4; ++j) acc[i][j] = (f32x4_t){0.f, 0.f, 0.f, 0.f};
    for (int k0 = 0; k0 < K; k0 += 32) {
        float4 va[8];
        float4 vb[4];
#pragma unroll
        for (int i = 0; i < 8; ++i) {
            const int p = i * 256 + tid;
            const int row = p >> 4, pc = p & 15;
            va[i] = *(const float4*)(xf + ((size_t)(m0 + row) * K + k0 + pc * 2) * 2);
        }
#pragma unroll
        for (int i = 0; i < 4; ++i) {
            const int q = i * 256 + tid;
            const int row = q >> 3, qc = q & 7;
            vb[i] = *(const float4*)(Wf + (size_t)(n0 + row) * K + k0 + qc * 4);
        }
        __syncthreads();
#pragma unroll
        for (int i = 0; i < 8; ++i) {
            const int p = i * 256 + tid;
            const int row = p >> 4, pc = p & 15;
            *(uint32_t*)&lA[row * 32 + pc * 2] =
                f32_to_bf16_rne(va[i].x) | (f32_to_bf16_rne(va[i].z) << 16);
        }
#pragma unroll
        for (int i = 0; i < 4; ++i) {
            const int q = i * 256 + tid;
            const int row = q >> 3, qc = q & 7;
            uint2 pk;
            pk.x = f32_to_bf16_rne(vb[i].x) | (f32_to_bf16_rne(vb[i].y) << 16);
            pk.y = f32_to_bf16_rne(vb[i].z) | (f32_to_bf16_rne(vb[i].w) << 16);
            *(uint2*)&lB[row * 32 + qc * 4] = pk;
        }
        __syncthreads();
        bf16x8_t af[4], bfr[4];
#pragma unroll
        for (int i = 0; i < 4; ++i)
            af[i] = *(const bf16x8_t*)&lA[(wr * 64 + i * 16 + lrow) * 32 + lkg * 8];
#pragma unroll
        for (int j = 0; j < 4; ++j)
            bfr[j] = *(const bf16x8_t*)&lB[(wc * 64 + j * 16 + lrow) * 32 + lkg * 8];
#pragma unroll
        for (int i = 0; i < 4; ++i)
#pragma unroll
            for (int j = 0; j < 4; ++j)
                acc[i][j] = __builtin_amdgcn_mfma_f32_16x16x32_bf16(af[i], bfr[j],
                                                                    acc[i][j], 0, 0, 0);
        __syncthreads();
    }
    const int gm = m0 + wr * 64;
    const int gn = n0 + wc * 64;
    float bcol[4];
#pragma unroll
    for (int j = 0; j < 4; ++j) bcol[j] = bias[gn + j * 16 + lrow];
#pragma unroll
    for (int i = 0; i < 4; ++i) {
#pragma unroll
        for (int r = 0; r < 4; ++r) {
            const int row = gm + i * 16 + lkg * 4 + r;
            const float vr = val[row];
            float2* orow = (float2*)(out + (size_t)row * N * 2);
#pragma unroll
            for (int j = 0; j < 4; ++j) {
                const int col = gn + j * 16 + lrow;
                float a = fmaxf(acc[i][j][r] + bcol[j], 0.f);
                orow[col] = make_float2(a, vr);
            }
        }
    }
}

extern "C" void kernel_launch(void* const* d_in, const int* in_sizes, int n_in,
                              void* d_out, int out_size, void* d_ws, size_t ws_size,
                              hipStream_t stream) {
    const float* x = (const float*)d_in[0];     // [B, DIN, 2]
    const float* W = (const float*)d_in[1];     // [DOUT, DIN]
    const float* b = (const float*)d_in[2];     // [DOUT]
    float* out = (float*)d_out;                 // [B, DOUT, 2]

    const int DOUT = in_sizes[2];
    const int DIN = in_sizes[1] / DOUT;
    const int B = in_sizes[0] / (2 * DIN);

    float* val = (float*)d_ws;
    const size_t aoff = 8192;
    const size_t abytes = (size_t)B * DIN * 2;
    const size_t wbytes = (size_t)DOUT * DIN * 2;
    const bool big = ws_size >= aoff + abytes + wbytes &&
                     (B % 128) == 0 && (DOUT % 256) == 0 && (DIN % 128) == 0;

    if (big) {
        uint32_t* abf = (uint32_t*)((char*)d_ws + aoff);
        uint32_t* wbf = (uint32_t*)((char*)d_ws + aoff + abytes);
        convert_x_stats<<<B, 256, 0, stream>>>((const float4*)x, abf, val, DIN);
        const int n4 = DOUT * DIN / 4;
        convert_w<<<(n4 + 255) / 256, 256, 0, stream>>>((const float4*)W, (uint2*)wbf, n4);
        (void)hipFuncSetAttribute((const void*)gemm_ph,
                                  hipFuncAttributeMaxDynamicSharedMemorySize, LDS_BYTES);
        dim3 grid(DOUT / 256, B / 128);
        gemm_ph<<<grid, 512, LDS_BYTES, stream>>>((const uint16_t*)abf,
                                                  (const uint16_t*)wbf,
                                                  b, val, out, B, DOUT, DIN);
    } else {
        convert_x_stats<<<B, 256, 0, stream>>>((const float4*)x, nullptr, val, DIN);
        dim3 grid(DOUT / 128, B / 128);
        gemm_fallback<<<grid, 256, 0, stream>>>(x, W, b, val, out, B, DOUT, DIN);
    }
}

// Round 11
// 96.823 us; speedup vs baseline: 1.1947x; 1.1947x over previous
//
#include <hip/hip_runtime.h>
#include <stdint.h>

// ---------------------------------------------------------------------------
// AVNNType1Linear: out[b,o,0] = relu(sum_k x[b,k,0]*W[o,k] + bias[o])
//                  out[b,o,1] = (sum_k x[b,k,0] + sum_k x[b,k,1]) / (2*K)
// M=2048, N=4096, K=4096 fp32.
// r11 = r4 revert (empirical winner: gemm 70us, MfmaUtil 43%, conflicts 0)
// + fused convert dispatch. r4 structure: BM=BN=128, BK=64, 4 waves (2x2),
// 2-deep LDS dbuf (64 KB) => 2 independent blocks/CU whose unsynchronized
// barriers overlap LDS-phase of one block with MFMA-phase of the other.
// ---------------------------------------------------------------------------

typedef __bf16 bf16x8_t __attribute__((ext_vector_type(8)));
typedef float f32x4_t __attribute__((ext_vector_type(4)));
typedef __attribute__((address_space(1))) void gvoid_t;
typedef __attribute__((address_space(3))) void lvoid_t;

__device__ __forceinline__ uint32_t f32_to_bf16_rne(float f) {
    uint32_t u = __float_as_uint(f);
    return (u + 0x7fffu + ((u >> 16) & 1u)) >> 16;
}

// 3-bit XOR swizzle (verified conflict-free in r3/r4)
__device__ __forceinline__ uint32_t swz(uint32_t b) {
    return b ^ (((b >> 7) & 7u) << 4);
}

__device__ __forceinline__ bf16x8_t ds_read128(uint32_t addr) {
    bf16x8_t d;
    asm volatile("ds_read_b128 %0, %1" : "=&v"(d) : "v"(addr));
    return d;
}

// ---- kernel 1: FUSED convert. Blocks [0,B): x-row -> bf16 + row stats.
//      Blocks [B, B+n4/256): W float4-chunk -> bf16. Bodies verbatim from
//      the r4-verified convert_x_stats / convert_w.
__global__ __launch_bounds__(256) void convert_fused(
    const float4* __restrict__ x4,   // [B][DIN/2] float4 = (a0,c0,a1,c1)
    uint32_t* __restrict__ abf,      // [B][DIN/2] packed 2xbf16
    float* __restrict__ val, int din, int nrowsx,
    const float4* __restrict__ w4, uint2* __restrict__ wbf, int n4) {
    const int t = threadIdx.x;
    if ((int)blockIdx.x < nrowsx) {
        const int row = blockIdx.x;
        const int f4pr = din >> 1;
        const float4* xr = x4 + (size_t)row * f4pr;
        float s = 0.f;
        uint32_t* ar = abf + ((size_t)row * din >> 1);
        for (int i = t; i < f4pr; i += 256) {
            float4 v = xr[i];
            s += (v.x + v.y) + (v.z + v.w);
            ar[i] = f32_to_bf16_rne(v.x) | (f32_to_bf16_rne(v.z) << 16);
        }
#pragma unroll
        for (int off = 32; off; off >>= 1) s += __shfl_down(s, off, 64);
        __shared__ float red[4];
        if ((t & 63) == 0) red[t >> 6] = s;
        __syncthreads();
        if (t == 0)
            val[row] = (red[0] + red[1] + red[2] + red[3]) / (float)(2 * din);
    } else {
        const int i = ((int)blockIdx.x - nrowsx) * 256 + t;
        if (i < n4) {
            float4 v = w4[i];
            uint2 p;
            p.x = f32_to_bf16_rne(v.x) | (f32_to_bf16_rne(v.y) << 16);
            p.y = f32_to_bf16_rne(v.z) | (f32_to_bf16_rne(v.w) << 16);
            wbf[i] = p;
        }
    }
}

// ---- kernel 2: BM=128 x BN=128 x BK=64 bf16 MFMA GEMM, 2 blocks/CU ----
// (verbatim r4 gemm2b)
#define BKB 128              // BK bytes per row (64 bf16)
#define A_SLAB 16384         // 128 x 64 x 2B
#define B_SLAB 16384         // 128 x 64 x 2B
#define B_BASE (2 * A_SLAB)
#define LDS_BYTES (B_BASE + 2 * B_SLAB)   // 64 KiB

__global__ __launch_bounds__(256, 2) void gemm2b(
    const uint16_t* __restrict__ Abf, const uint16_t* __restrict__ Wbf,
    const float* __restrict__ bias, const float* __restrict__ val,
    float* __restrict__ out, int M, int N, int K) {
    extern __shared__ char lds[];
    const uint32_t lds0 = (uint32_t)(uintptr_t)(lvoid_t*)lds;

    const int tid = threadIdx.x;
    const int wv = tid >> 6;
    const int lane = tid & 63;
    const int lrow = lane & 15, lkg = lane >> 4;
    const int m0 = blockIdx.y * 128;
    const int n0 = blockIdx.x * 128;
    const int wr = wv >> 1, wc = wv & 1;

    // staging: linear LDS dest chunk c=l*256+tid holds logical tile byte
    // swz(c*16) -> pre-swizzled per-lane global source (rule #21)
    uint32_t asrc[4], bsrc[4];
#pragma unroll
    for (int l = 0; l < 4; ++l) {
        uint32_t sb = swz((uint32_t)(l * 256 + tid) * 16u);
        asrc[l] = (uint32_t)(m0 + (int)(sb >> 7)) * (uint32_t)(K * 2) + (sb & 127u);
        bsrc[l] = (uint32_t)(n0 + (int)(sb >> 7)) * (uint32_t)(K * 2) + (sb & 127u);
    }
    // swizzled LDS read offsets, k-step 0; k-step 1 = ^64 (bit6 in swz field)
    uint32_t ard[4], brd[4];
#pragma unroll
    for (int m = 0; m < 4; ++m)
        ard[m] = swz((uint32_t)(wr * 64 + m * 16 + lrow) * 128u + (uint32_t)(lkg * 16));
#pragma unroll
    for (int n = 0; n < 4; ++n)
        brd[n] = swz((uint32_t)(wc * 64 + n * 16 + lrow) * 128u + (uint32_t)(lkg * 16));

    f32x4_t acc[4][4];
#pragma unroll
    for (int i = 0; i < 4; ++i)
#pragma unroll
        for (int j = 0; j < 4; ++j) acc[i][j] = (f32x4_t){0.f, 0.f, 0.f, 0.f};

    const int NT = K >> 6;

    auto STAGE = [&](int tt) {   // 8 global_load_lds (A:4, B:4) -> slot tt&1
        const int slot = tt & 1;
#pragma unroll
        for (int l = 0; l < 4; ++l) {
            const char* srcA = (const char*)Abf + asrc[l] + (size_t)tt * BKB;
            char* dstA = lds + slot * A_SLAB + l * 4096 + wv * 1024;
            __builtin_amdgcn_global_load_lds((gvoid_t*)srcA, (lvoid_t*)dstA, 16, 0, 0);
            const char* srcB = (const char*)Wbf + bsrc[l] + (size_t)tt * BKB;
            char* dstB = lds + B_BASE + slot * B_SLAB + l * 4096 + wv * 1024;
            __builtin_amdgcn_global_load_lds((gvoid_t*)srcB, (lvoid_t*)dstB, 16, 0, 0);
        }
    };

    // prologue: stage tile 0, drain, barrier
    STAGE(0);
    asm volatile("s_waitcnt vmcnt(0)" ::: "memory");
    __builtin_amdgcn_sched_barrier(0);
    __builtin_amdgcn_s_barrier();

    for (int t = 0; t < NT; ++t) {
        const uint32_t la = lds0 + (t & 1) * A_SLAB;
        const uint32_t lb = lds0 + B_BASE + (t & 1) * B_SLAB;
        // prefetch next tile into the other slot (its readers were fenced by
        // the barrier that ended tile t-1)
        if (t + 1 < NT) STAGE(t + 1);
        bf16x8_t af0[4], bf0[4], af1[4], bf1[4];
#pragma unroll
        for (int m = 0; m < 4; ++m) af0[m] = ds_read128(la + ard[m]);
#pragma unroll
        for (int n = 0; n < 4; ++n) bf0[n] = ds_read128(lb + brd[n]);
#pragma unroll
        for (int m = 0; m < 4; ++m) af1[m] = ds_read128(la + (ard[m] ^ 64u));
#pragma unroll
        for (int n = 0; n < 4; ++n) bf1[n] = ds_read128(lb + (brd[n] ^ 64u));
        // k0 fragments ready when <=8 ds ops outstanding
        asm volatile("s_waitcnt lgkmcnt(8)" ::: "memory");
        __builtin_amdgcn_sched_barrier(0);
        __builtin_amdgcn_s_setprio(1);
#pragma unroll
        for (int m = 0; m < 4; ++m)
#pragma unroll
            for (int n = 0; n < 4; ++n)
                acc[m][n] = __builtin_amdgcn_mfma_f32_16x16x32_bf16(af0[m], bf0[n],
                                                                    acc[m][n], 0, 0, 0);
        __builtin_amdgcn_s_setprio(0);
        asm volatile("s_waitcnt lgkmcnt(0)" ::: "memory");
        __builtin_amdgcn_sched_barrier(0);
        __builtin_amdgcn_s_setprio(1);
#pragma unroll
        for (int m = 0; m < 4; ++m)
#pragma unroll
            for (int n = 0; n < 4; ++n)
                acc[m][n] = __builtin_amdgcn_mfma_f32_16x16x32_bf16(af1[m], bf1[n],
                                                                    acc[m][n], 0, 0, 0);
        __builtin_amdgcn_s_setprio(0);
        if (t + 1 < NT) {
            // next tile's staging must be complete (sibling block on the CU
            // covers this drain)
            asm volatile("s_waitcnt vmcnt(0)" ::: "memory");
            __builtin_amdgcn_sched_barrier(0);
            __builtin_amdgcn_s_barrier();
        }
    }

    // ---------------- epilogue: bias + relu + val interleave ----------------
    const int gmb = m0 + wr * 64;
    const int gnb = n0 + wc * 64;
    float bcol[4];
#pragma unroll
    for (int n = 0; n < 4; ++n) bcol[n] = bias[gnb + n * 16 + lrow];
#pragma unroll
    for (int m = 0; m < 4; ++m) {
#pragma unroll
        for (int r = 0; r < 4; ++r) {
            const int row = gmb + m * 16 + lkg * 4 + r;
            const float vr = val[row];
            float2* orow = (float2*)(out + (size_t)row * N * 2);
#pragma unroll
            for (int n = 0; n < 4; ++n) {
                const int col = gnb + n * 16 + lrow;
                float a = fmaxf(acc[m][n][r] + bcol[n], 0.f);
                orow[col] = make_float2(a, vr);
            }
        }
    }
}

// ---- fallback kernels (small ws): r0 path, known-correct ----
__global__ __launch_bounds__(256) void convert_x_stats(
    const float4* __restrict__ x4, uint32_t* __restrict__ abf,
    float* __restrict__ val, int din) {
    const int row = blockIdx.x;
    const int t = threadIdx.x;
    const int f4pr = din >> 1;
    const float4* xr = x4 + (size_t)row * f4pr;
    float s = 0.f;
    for (int i = t; i < f4pr; i += 256) {
        float4 v = xr[i];
        s += (v.x + v.y) + (v.z + v.w);
    }
#pragma unroll
    for (int off = 32; off; off >>= 1) s += __shfl_down(s, off, 64);
    __shared__ float red[4];
    if ((t & 63) == 0) red[t >> 6] = s;
    __syncthreads();
    if (t == 0) val[row] = (red[0] + red[1] + red[2] + red[3]) / (float)(2 * din);
}

__global__ __launch_bounds__(256) void gemm_fallback(
    const float* __restrict__ xf, const float* __restrict__ Wf,
    const float* __restrict__ bias, const float* __restrict__ val,
    float* __restrict__ out, int M, int N, int K) {
    __shared__ uint16_t lA[128 * 32];
    __shared__ uint16_t lB[128 * 32];
    const int tid = threadIdx.x;
    const int wv = tid >> 6;
    const int lane = tid & 63;
    const int lrow = lane & 15;
    const int lkg = lane >> 4;
    const int m0 = blockIdx.y * 128;
    const int n0 = blockIdx.x * 128;
    const int wr = wv >> 1, wc = wv & 1;
    f32x4_t acc[4][4];
#pragma unroll
    for (int i = 0; i < 4; ++i)
#pragma unroll
        for (int j = 0; j < 4; ++j) acc[i][j] = (f32x4_t){0.f, 0.f, 0.f, 0.f};
    for (int k0 = 0; k0 < K; k0 += 32) {
        float4 va[8];
        float4 vb[4];
#pragma unroll
        for (int i = 0; i < 8; ++i) {
            const int p = i * 256 + tid;
            const int row = p >> 4, pc = p & 15;
            va[i] = *(const float4*)(xf + ((size_t)(m0 + row) * K + k0 + pc * 2) * 2);
        }
#pragma unroll
        for (int i = 0; i < 4; ++i) {
            const int q = i * 256 + tid;
            const int row = q >> 3, qc = q & 7;
            vb[i] = *(const float4*)(Wf + (size_t)(n0 + row) * K + k0 + qc * 4);
        }
        __syncthreads();
#pragma unroll
        for (int i = 0; i < 8; ++i) {
            const int p = i * 256 + tid;
            const int row = p >> 4, pc = p & 15;
            *(uint32_t*)&lA[row * 32 + pc * 2] =
                f32_to_bf16_rne(va[i].x) | (f32_to_bf16_rne(va[i].z) << 16);
        }
#pragma unroll
        for (int i = 0; i < 4; ++i) {
            const int q = i * 256 + tid;
            const int row = q >> 3, qc = q & 7;
            uint2 pk;
            pk.x = f32_to_bf16_rne(vb[i].x) | (f32_to_bf16_rne(vb[i].y) << 16);
            pk.y = f32_to_bf16_rne(vb[i].z) | (f32_to_bf16_rne(vb[i].w) << 16);
            *(uint2*)&lB[row * 32 + qc * 4] = pk;
        }
        __syncthreads();
        bf16x8_t af[4], bfr[4];
#pragma unroll
        for (int i = 0; i < 4; ++i)
            af[i] = *(const bf16x8_t*)&lA[(wr * 64 + i * 16 + lrow) * 32 + lkg * 8];
#pragma unroll
        for (int j = 0; j < 4; ++j)
            bfr[j] = *(const bf16x8_t*)&lB[(wc * 64 + j * 16 + lrow) * 32 + lkg * 8];
#pragma unroll
        for (int i = 0; i < 4; ++i)
#pragma unroll
            for (int j = 0; j < 4; ++j)
                acc[i][j] = __builtin_amdgcn_mfma_f32_16x16x32_bf16(af[i], bfr[j],
                                                                    acc[i][j], 0, 0, 0);
        __syncthreads();
    }
    const int gm = m0 + wr * 64;
    const int gn = n0 + wc * 64;
    float bcol[4];
#pragma unroll
    for (int j = 0; j < 4; ++j) bcol[j] = bias[gn + j * 16 + lrow];
#pragma unroll
    for (int i = 0; i < 4; ++i) {
#pragma unroll
        for (int r = 0; r < 4; ++r) {
            const int row = gm + i * 16 + lkg * 4 + r;
            const float vr = val[row];
            float2* orow = (float2*)(out + (size_t)row * N * 2);
#pragma unroll
            for (int j = 0; j < 4; ++j) {
                const int col = gn + j * 16 + lrow;
                float a = fmaxf(acc[i][j][r] + bcol[j], 0.f);
                orow[col] = make_float2(a, vr);
            }
        }
    }
}

extern "C" void kernel_launch(void* const* d_in, const int* in_sizes, int n_in,
                              void* d_out, int out_size, void* d_ws, size_t ws_size,
                              hipStream_t stream) {
    const float* x = (const float*)d_in[0];     // [B, DIN, 2]
    const float* W = (const float*)d_in[1];     // [DOUT, DIN]
    const float* b = (const float*)d_in[2];     // [DOUT]
    float* out = (float*)d_out;                 // [B, DOUT, 2]

    const int DOUT = in_sizes[2];
    const int DIN = in_sizes[1] / DOUT;
    const int B = in_sizes[0] / (2 * DIN);

    float* val = (float*)d_ws;
    const size_t aoff = 8192;
    const size_t abytes = (size_t)B * DIN * 2;
    const size_t wbytes = (size_t)DOUT * DIN * 2;
    const bool big = ws_size >= aoff + abytes + wbytes &&
                     (B % 128) == 0 && (DOUT % 128) == 0 && (DIN % 64) == 0;

    if (big) {
        uint32_t* abf = (uint32_t*)((char*)d_ws + aoff);
        uint32_t* wbf = (uint32_t*)((char*)d_ws + aoff + abytes);
        const int n4 = DOUT * DIN / 4;
        const int nwgW = (n4 + 255) / 256;
        convert_fused<<<B + nwgW, 256, 0, stream>>>(
            (const float4*)x, abf, val, DIN, B, (const float4*)W, (uint2*)wbf, n4);
        (void)hipFuncSetAttribute((const void*)gemm2b,
                                  hipFuncAttributeMaxDynamicSharedMemorySize, LDS_BYTES);
        dim3 grid(DOUT / 128, B / 128);
        gemm2b<<<grid, 256, LDS_BYTES, stream>>>((const uint16_t*)abf, (const uint16_t*)wbf,
                                                 b, val, out, B, DOUT, DIN);
    } else {
        convert_x_stats<<<B, 256, 0, stream>>>((const float4*)x, nullptr, val, DIN);
        dim3 grid(DOUT / 128, B / 128);
        gemm_fallback<<<grid, 256, 0, stream>>>(x, W, b, val, out, B, DOUT, DIN);
    }
}